// Round 1
// baseline (615.983 us; speedup 1.0000x reference)
//
#include <hip/hip_runtime.h>
#include <hip/hip_bf16.h>

typedef __attribute__((ext_vector_type(4))) float f32x4;
typedef __attribute__((ext_vector_type(8))) short short8;

#define BM 128
#define BN 128
#define BK 64
#define LDA 72   // LDS row stride in bf16 elements (64 + 8 pad -> 144B rows, uniform bank spread)

__device__ __forceinline__ short f2bf(float f) {
    union { __hip_bfloat16 h; short s; } u;
    u.h = __float2bfloat16(f);
    return u.s;
}

// ---------------------------------------------------------------------------
// Prepass: kernels [R*D=4096][F=1024] fp32  ->  Kt [F=1024][K=4096] bf16
// ---------------------------------------------------------------------------
__global__ void kconv_transpose(const float* __restrict__ kern,
                                __hip_bfloat16* __restrict__ Kt) {
    __shared__ float tile[32][33];
    int k0 = blockIdx.x << 5;   // source row (k) tile
    int f0 = blockIdx.y << 5;   // source col (f) tile
    int tx = threadIdx.x & 31;
    int ty = threadIdx.x >> 5;  // 0..7
#pragma unroll
    for (int q = 0; q < 4; q++) {
        int k = k0 + ty + q * 8;
        tile[ty + q * 8][tx] = kern[(size_t)k * 1024 + f0 + tx];
    }
    __syncthreads();
#pragma unroll
    for (int q = 0; q < 4; q++) {
        int f = f0 + ty + q * 8;
        Kt[((size_t)f << 12) + k0 + tx] = __float2bfloat16(tile[tx][ty + q * 8]);
    }
}

// ---------------------------------------------------------------------------
// Main GEMM: out[M=32768][1024] = windowed(x) [M][4096] * Kcat [4096][1024]
// 128x128 tile, BK=64, 4 waves (2x2), 16x16x32 bf16 MFMA, 4x4 frags/wave.
// ---------------------------------------------------------------------------
__global__ void __launch_bounds__(256, 2)
altconv_gemm(const float* __restrict__ x,            // [4][8192][1024]
             const __hip_bfloat16* __restrict__ Kt,  // [1024][4096]
             const float* __restrict__ biases,       // [4][1024]
             float* __restrict__ out) {              // [4][8192][1024]
    __shared__ alignas(16) __hip_bfloat16 As[BM * LDA];
    __shared__ alignas(16) __hip_bfloat16 Bs[BN * LDA];

    // XCD-aware bijective swizzle (grid = 2048, 2048 % 8 == 0)
    int bid  = blockIdx.x;
    int tid2 = (bid & 7) * 256 + (bid >> 3);
    int mt = tid2 >> 3;          // 0..255 M-tiles
    int nt = tid2 & 7;           // 0..7   N-tiles
    int bm0   = mt * BM;         // global out-row
    int batch = bm0 >> 13;       // /8192 (BM | 8192 so tile is within one batch)
    int srow0 = bm0 & 8191;
    int bn0   = nt * BN;
    const float* xb = x + (((size_t)batch << 13) << 10);

    int t    = threadIdx.x;
    int lane = t & 63;
    int wid  = t >> 6;
    int wr = wid >> 1, wc = wid & 1;

    // staging mapping: 2 threads per row, each covers 32 consecutive k-elements
    int sr   = t >> 1;           // row 0..127
    int sseg = t & 1;            // 0/1

    f32x4 acc[4][4];
#pragma unroll
    for (int m = 0; m < 4; m++)
#pragma unroll
        for (int n = 0; n < 4; n++) acc[m][n] = (f32x4){0.f, 0.f, 0.f, 0.f};

    f32x4 aR[8];   // 32 fp32 of A (x)
    f32x4 bR[4];   // 32 bf16 of B (Kt), carried as 16B words

#define LOAD_TILE(kt) do {                                                        \
        int tap = (kt) >> 4;                                                      \
        int c0  = ((kt) & 15) << 6;                                               \
        int s   = srow0 + sr - tap;                                               \
        if (s >= 0) {                                                             \
            const float* asrc = xb + ((size_t)s << 10) + c0 + sseg * 32;          \
            _Pragma("unroll")                                                     \
            for (int j = 0; j < 8; j++)                                           \
                aR[j] = *reinterpret_cast<const f32x4*>(asrc + j * 4);            \
        } else {                                                                  \
            _Pragma("unroll")                                                     \
            for (int j = 0; j < 8; j++) aR[j] = (f32x4){0.f, 0.f, 0.f, 0.f};      \
        }                                                                         \
        const __hip_bfloat16* bsrc =                                              \
            Kt + ((size_t)(bn0 + sr) << 12) + (kt) * 64 + sseg * 32;              \
        _Pragma("unroll")                                                         \
        for (int j = 0; j < 4; j++)                                               \
            bR[j] = *reinterpret_cast<const f32x4*>(bsrc + j * 8);                \
    } while (0)

#define STORE_TILE() do {                                                         \
        _Pragma("unroll")                                                         \
        for (int j = 0; j < 4; j++) {                                             \
            short8 pk;                                                            \
            f32x4 lo = aR[2 * j], hi = aR[2 * j + 1];                             \
            pk[0] = f2bf(lo[0]); pk[1] = f2bf(lo[1]);                             \
            pk[2] = f2bf(lo[2]); pk[3] = f2bf(lo[3]);                             \
            pk[4] = f2bf(hi[0]); pk[5] = f2bf(hi[1]);                             \
            pk[6] = f2bf(hi[2]); pk[7] = f2bf(hi[3]);                             \
            *reinterpret_cast<short8*>(&As[sr * LDA + (sseg * 4 + j) * 8]) = pk;  \
        }                                                                         \
        _Pragma("unroll")                                                         \
        for (int j = 0; j < 4; j++)                                               \
            *reinterpret_cast<f32x4*>(&Bs[sr * LDA + (sseg * 4 + j) * 8]) = bR[j];\
    } while (0)

#define COMPUTE() do {                                                            \
        _Pragma("unroll")                                                         \
        for (int ks = 0; ks < 2; ks++) {                                          \
            short8 af[4], bfv[4];                                                 \
            int koff = ks * 32 + ((lane >> 4) << 3);                              \
            int frr  = lane & 15;                                                 \
            _Pragma("unroll")                                                     \
            for (int m = 0; m < 4; m++)                                           \
                af[m] = *reinterpret_cast<const short8*>(                         \
                    &As[(wr * 64 + m * 16 + frr) * LDA + koff]);                  \
            _Pragma("unroll")                                                     \
            for (int n = 0; n < 4; n++)                                           \
                bfv[n] = *reinterpret_cast<const short8*>(                        \
                    &Bs[(wc * 64 + n * 16 + frr) * LDA + koff]);                  \
            _Pragma("unroll")                                                     \
            for (int m = 0; m < 4; m++)                                           \
                _Pragma("unroll")                                                 \
                for (int n = 0; n < 4; n++)                                       \
                    acc[m][n] = __builtin_amdgcn_mfma_f32_16x16x32_bf16(          \
                        af[m], bfv[n], acc[m][n], 0, 0, 0);                       \
        }                                                                         \
    } while (0)

    LOAD_TILE(0);
    STORE_TILE();
    __syncthreads();
    for (int kt = 0; kt < 63; kt++) {
        LOAD_TILE(kt + 1);   // issue global loads early -> overlap with MFMA
        COMPUTE();           // ds_read + MFMA on tile kt
        __syncthreads();
        STORE_TILE();        // cvt + write tile kt+1
        __syncthreads();
    }
    COMPUTE();               // tile 63

    // epilogue: C/D layout col=lane&15, row=(lane>>4)*4+j  [measured m89]
    int fr   = lane & 15;
    int rowg = (lane >> 4) << 2;
#pragma unroll
    for (int n = 0; n < 4; n++) {
        int gc = bn0 + wc * 64 + n * 16 + fr;
        float bsum = biases[gc] + biases[1024 + gc] + biases[2048 + gc] + biases[3072 + gc];
#pragma unroll
        for (int m = 0; m < 4; m++) {
            size_t gr = (size_t)(bm0 + wr * 64 + m * 16 + rowg);
#pragma unroll
            for (int j = 0; j < 4; j++) {
                out[(gr + j) * 1024 + gc] = acc[m][n][j] + bsum;
            }
        }
    }
#undef LOAD_TILE
#undef STORE_TILE
#undef COMPUTE
}

// ---------------------------------------------------------------------------
// Fallback (only if ws too small): straightforward fp32, correct but slow.
// ---------------------------------------------------------------------------
__global__ void fallback_conv(const float* __restrict__ x, const float* __restrict__ kern,
                              const float* __restrict__ biases, float* __restrict__ out) {
    __shared__ float xs[1024];
    int row = blockIdx.x;                       // 0..32767
    int f = (blockIdx.y << 8) + threadIdx.x;    // 0..1023
    int batch = row >> 13, s = row & 8191;
    const float* xb = x + (((size_t)batch << 13) << 10);
    float acc = 0.f;
    for (int tap = 0; tap < 4; tap++) {
        int ss = s - tap;
        __syncthreads();
        for (int i = threadIdx.x; i < 1024; i += 256)
            xs[i] = (ss >= 0) ? xb[((size_t)ss << 10) + i] : 0.f;
        __syncthreads();
        const float* kp = kern + ((size_t)tap << 20) + f;
        float a = 0.f;
        for (int d = 0; d < 1024; d++) a += xs[d] * kp[(size_t)d << 10];
        acc += a + biases[(tap << 10) + f];
    }
    out[((size_t)row << 10) + f] = acc;
}

extern "C" void kernel_launch(void* const* d_in, const int* in_sizes, int n_in,
                              void* d_out, int out_size, void* d_ws, size_t ws_size,
                              hipStream_t stream) {
    const float* x      = (const float*)d_in[0];
    const float* kern   = (const float*)d_in[1];
    const float* biases = (const float*)d_in[2];
    float* out = (float*)d_out;

    const size_t kt_bytes = (size_t)4096 * 1024 * sizeof(__hip_bfloat16);
    if (ws_size >= kt_bytes) {
        __hip_bfloat16* Kt = (__hip_bfloat16*)d_ws;
        kconv_transpose<<<dim3(128, 32), 256, 0, stream>>>(kern, Kt);
        altconv_gemm<<<2048, 256, 0, stream>>>(x, Kt, biases, out);
    } else {
        fallback_conv<<<dim3(32768, 4), 256, 0, stream>>>(x, kern, biases, out);
    }
}

// Round 2
// 328.125 us; speedup vs baseline: 1.8773x; 1.8773x over previous
//
#include <hip/hip_runtime.h>
#include <hip/hip_bf16.h>

typedef __attribute__((ext_vector_type(4))) float f32x4;
typedef __attribute__((ext_vector_type(8))) short short8;

#define XROWS 8195            // 3 guard rows + 8192
#define XBATCH (XROWS * 1024) // elems per padded batch

__device__ __forceinline__ short f2bf(float f) {
    union { __hip_bfloat16 h; short s; } u;
    u.h = __float2bfloat16(f);
    return u.s;
}

__device__ __forceinline__ void async16(const void* g, void* l) {
    __builtin_amdgcn_global_load_lds(
        (const __attribute__((address_space(1))) unsigned int*)g,
        (__attribute__((address_space(3))) unsigned int*)l, 16, 0, 0);
}

// ---------------------------------------------------------------------------
// Prepass 1: x fp32 [4][8192][1024] -> Xbf bf16 [4][3+8192][1024], guard=0
// ---------------------------------------------------------------------------
__global__ void x_to_bf16(const float* __restrict__ x,
                          __hip_bfloat16* __restrict__ Xbf) {
    size_t idx = (size_t)blockIdx.x * blockDim.x + threadIdx.x;
    // zero the 4*3*1024 guard elems (1536 short8 stores)
    if (idx < 1536) {
        int b = (int)(idx / 384);
        int r = (int)(idx % 384);
        *reinterpret_cast<short8*>(&Xbf[(size_t)b * XBATCH + r * 8]) =
            (short8){0, 0, 0, 0, 0, 0, 0, 0};
    }
    size_t stride = (size_t)gridDim.x * blockDim.x;
    const size_t nvec = (size_t)4 * 8192 * 1024 / 8;  // 4194304
    for (size_t v = idx; v < nvec; v += stride) {
        size_t e = v * 8;
        int b = (int)(e >> 23);
        size_t rem = e & ((1u << 23) - 1);
        f32x4 lo = *reinterpret_cast<const f32x4*>(x + e);
        f32x4 hi = *reinterpret_cast<const f32x4*>(x + e + 4);
        short8 pk;
        pk[0] = f2bf(lo[0]); pk[1] = f2bf(lo[1]); pk[2] = f2bf(lo[2]); pk[3] = f2bf(lo[3]);
        pk[4] = f2bf(hi[0]); pk[5] = f2bf(hi[1]); pk[6] = f2bf(hi[2]); pk[7] = f2bf(hi[3]);
        *reinterpret_cast<short8*>(&Xbf[(size_t)b * XBATCH + 3 * 1024 + rem]) = pk;
    }
}

// ---------------------------------------------------------------------------
// Prepass 2: kernels [R*D=4096][F=1024] fp32 -> Kt [F=1024][K=4096] bf16
// ---------------------------------------------------------------------------
__global__ void kconv_transpose(const float* __restrict__ kern,
                                __hip_bfloat16* __restrict__ Kt) {
    __shared__ float tile[32][33];
    int k0 = blockIdx.x << 5;
    int f0 = blockIdx.y << 5;
    int tx = threadIdx.x & 31;
    int ty = threadIdx.x >> 5;
#pragma unroll
    for (int q = 0; q < 4; q++) {
        int k = k0 + ty + q * 8;
        tile[ty + q * 8][tx] = kern[(size_t)k * 1024 + f0 + tx];
    }
    __syncthreads();
#pragma unroll
    for (int q = 0; q < 4; q++) {
        int f = f0 + ty + q * 8;
        Kt[((size_t)f << 12) + k0 + tx] = __float2bfloat16(tile[tx][ty + q * 8]);
    }
}

// ---------------------------------------------------------------------------
// Main GEMM (m97 structure): out[32768][1024] = win(Xbf)[M][4096] * Kt^T
// 128x128 tile, BK=64, 4 waves (2x2), global_load_lds width=16, linear LDS.
// ---------------------------------------------------------------------------
__global__ void __launch_bounds__(256, 3)
altconv_gemm2(const __hip_bfloat16* __restrict__ Xbf,  // [4][8195][1024]
              const __hip_bfloat16* __restrict__ Kt,   // [1024][4096]
              const float* __restrict__ biases,        // [4][1024]
              float* __restrict__ out) {               // [32768][1024]
    __shared__ alignas(16) __hip_bfloat16 As[128 * 64];
    __shared__ alignas(16) __hip_bfloat16 Bs[128 * 64];

    // bijective XCD swizzle (2048 % 8 == 0); nt fastest within an XCD chunk
    int bid  = blockIdx.x;
    int tid2 = (bid & 7) * 256 + (bid >> 3);
    int mt = tid2 >> 3;
    int nt = tid2 & 7;
    int bm0   = mt << 7;
    int batch = bm0 >> 13;
    int srow0 = bm0 & 8191;
    int bn0   = nt << 7;
    const __hip_bfloat16* xb = Xbf + (size_t)batch * XBATCH;

    int t    = threadIdx.x;
    int lane = t & 63;
    int wid  = t >> 6;
    int wr = wid >> 1, wc = wid & 1;

    // staging geometry: wave w, instr j covers tile rows w*32+j*8 .. +8
    int rbase = (wid << 5) + (lane >> 3);  // + j*8
    int ce    = (lane & 7) << 3;           // column element offset (8 bf16 = 16B)

    f32x4 acc[4][4];
#pragma unroll
    for (int m = 0; m < 4; m++)
#pragma unroll
        for (int n = 0; n < 4; n++) acc[m][n] = (f32x4){0.f, 0.f, 0.f, 0.f};

#define STAGE(kt) do {                                                         \
        int tap = (kt) >> 4;                                                   \
        int c0  = ((kt) & 15) << 6;                                            \
        const __hip_bfloat16* aS =                                             \
            xb + (size_t)(srow0 + 3 - tap) * 1024 + c0 + ce;                   \
        const __hip_bfloat16* bS =                                             \
            Kt + ((size_t)bn0 << 12) + ((size_t)(kt) << 6) + ce;               \
        _Pragma("unroll")                                                      \
        for (int j = 0; j < 4; j++) {                                          \
            int r = rbase + j * 8;                                             \
            async16(aS + (size_t)r * 1024, &As[r * 64 + ce]);                  \
            async16(bS + ((size_t)r << 12), &Bs[r * 64 + ce]);                 \
        }                                                                      \
    } while (0)

#define COMPUTE() do {                                                         \
        _Pragma("unroll")                                                      \
        for (int ks = 0; ks < 2; ks++) {                                       \
            short8 af[4], bfv[4];                                              \
            int koff = ks * 32 + ((lane >> 4) << 3);                           \
            int frr  = lane & 15;                                              \
            _Pragma("unroll")                                                  \
            for (int m = 0; m < 4; m++)                                        \
                af[m] = *reinterpret_cast<const short8*>(                      \
                    &As[(wr * 64 + m * 16 + frr) * 64 + koff]);                \
            _Pragma("unroll")                                                  \
            for (int n = 0; n < 4; n++)                                        \
                bfv[n] = *reinterpret_cast<const short8*>(                     \
                    &Bs[(wc * 64 + n * 16 + frr) * 64 + koff]);                \
            _Pragma("unroll")                                                  \
            for (int m = 0; m < 4; m++)                                        \
                _Pragma("unroll")                                              \
                for (int n = 0; n < 4; n++)                                    \
                    acc[m][n] = __builtin_amdgcn_mfma_f32_16x16x32_bf16(       \
                        af[m], bfv[n], acc[m][n], 0, 0, 0);                    \
        }                                                                      \
    } while (0)

    STAGE(0);
    for (int kt = 0; kt < 64; kt++) {
        __syncthreads();           // compiler drains vmcnt(0) here (m97 stall)
        COMPUTE();
        __syncthreads();
        if (kt < 63) STAGE(kt + 1);
    }

    // epilogue: C/D layout col=lane&15, row=(lane>>4)*4+j  [m89]
    int fr   = lane & 15;
    int rowg = (lane >> 4) << 2;
#pragma unroll
    for (int n = 0; n < 4; n++) {
        int gc = bn0 + wc * 64 + n * 16 + fr;
        float bsum = biases[gc] + biases[1024 + gc] + biases[2048 + gc] + biases[3072 + gc];
#pragma unroll
        for (int m = 0; m < 4; m++) {
            size_t gr = (size_t)(bm0 + wr * 64 + m * 16 + rowg);
#pragma unroll
            for (int j = 0; j < 4; j++) {
                out[(gr + j) * 1024 + gc] = acc[m][n][j] + bsum;
            }
        }
    }
#undef STAGE
#undef COMPUTE
}

// ---------------------------------------------------------------------------
// Fallback A (ws >= 8.4MB only): round-1 reg-staged GEMM (verified, 616us)
// ---------------------------------------------------------------------------
#define LDA 72
__global__ void __launch_bounds__(256, 2)
altconv_gemm(const float* __restrict__ x,
             const __hip_bfloat16* __restrict__ Kt,
             const float* __restrict__ biases,
             float* __restrict__ out) {
    __shared__ alignas(16) __hip_bfloat16 As[128 * LDA];
    __shared__ alignas(16) __hip_bfloat16 Bs[128 * LDA];

    int bid  = blockIdx.x;
    int tid2 = (bid & 7) * 256 + (bid >> 3);
    int mt = tid2 >> 3;
    int nt = tid2 & 7;
    int bm0   = mt * 128;
    int batch = bm0 >> 13;
    int srow0 = bm0 & 8191;
    int bn0   = nt * 128;
    const float* xb = x + (((size_t)batch << 13) << 10);

    int t    = threadIdx.x;
    int lane = t & 63;
    int wid  = t >> 6;
    int wr = wid >> 1, wc = wid & 1;
    int sr   = t >> 1;
    int sseg = t & 1;

    f32x4 acc[4][4];
#pragma unroll
    for (int m = 0; m < 4; m++)
#pragma unroll
        for (int n = 0; n < 4; n++) acc[m][n] = (f32x4){0.f, 0.f, 0.f, 0.f};

    f32x4 aR[8];
    f32x4 bR[4];

#define LOAD_TILE(kt) do {                                                        \
        int tap = (kt) >> 4;                                                      \
        int c0  = ((kt) & 15) << 6;                                               \
        int s   = srow0 + sr - tap;                                               \
        if (s >= 0) {                                                             \
            const float* asrc = xb + ((size_t)s << 10) + c0 + sseg * 32;          \
            _Pragma("unroll")                                                     \
            for (int j = 0; j < 8; j++)                                           \
                aR[j] = *reinterpret_cast<const f32x4*>(asrc + j * 4);            \
        } else {                                                                  \
            _Pragma("unroll")                                                     \
            for (int j = 0; j < 8; j++) aR[j] = (f32x4){0.f, 0.f, 0.f, 0.f};      \
        }                                                                         \
        const __hip_bfloat16* bsrc =                                              \
            Kt + ((size_t)(bn0 + sr) << 12) + (kt) * 64 + sseg * 32;              \
        _Pragma("unroll")                                                         \
        for (int j = 0; j < 4; j++)                                              \
            bR[j] = *reinterpret_cast<const f32x4*>(bsrc + j * 8);                \
    } while (0)

#define STORE_TILE() do {                                                         \
        _Pragma("unroll")                                                         \
        for (int j = 0; j < 4; j++) {                                             \
            short8 pk;                                                            \
            f32x4 lo = aR[2 * j], hi = aR[2 * j + 1];                             \
            pk[0] = f2bf(lo[0]); pk[1] = f2bf(lo[1]);                             \
            pk[2] = f2bf(lo[2]); pk[3] = f2bf(lo[3]);                             \
            pk[4] = f2bf(hi[0]); pk[5] = f2bf(hi[1]);                             \
            pk[6] = f2bf(hi[2]); pk[7] = f2bf(hi[3]);                             \
            *reinterpret_cast<short8*>(&As[sr * LDA + (sseg * 4 + j) * 8]) = pk;  \
        }                                                                         \
        _Pragma("unroll")                                                         \
        for (int j = 0; j < 4; j++)                                               \
            *reinterpret_cast<f32x4*>(&Bs[sr * LDA + (sseg * 4 + j) * 8]) = bR[j];\
    } while (0)

#define COMPUTE1() do {                                                           \
        _Pragma("unroll")                                                         \
        for (int ks = 0; ks < 2; ks++) {                                          \
            short8 af[4], bfv[4];                                                 \
            int koff = ks * 32 + ((lane >> 4) << 3);                              \
            int frr  = lane & 15;                                                 \
            _Pragma("unroll")                                                     \
            for (int m = 0; m < 4; m++)                                           \
                af[m] = *reinterpret_cast<const short8*>(                         \
                    &As[(wr * 64 + m * 16 + frr) * LDA + koff]);                  \
            _Pragma("unroll")                                                     \
            for (int n = 0; n < 4; n++)                                           \
                bfv[n] = *reinterpret_cast<const short8*>(                        \
                    &Bs[(wc * 64 + n * 16 + frr) * LDA + koff]);                  \
            _Pragma("unroll")                                                     \
            for (int m = 0; m < 4; m++)                                           \
                _Pragma("unroll")                                                 \
                for (int n = 0; n < 4; n++)                                       \
                    acc[m][n] = __builtin_amdgcn_mfma_f32_16x16x32_bf16(          \
                        af[m], bfv[n], acc[m][n], 0, 0, 0);                       \
        }                                                                         \
    } while (0)

    LOAD_TILE(0);
    STORE_TILE();
    __syncthreads();
    for (int kt = 0; kt < 63; kt++) {
        LOAD_TILE(kt + 1);
        COMPUTE1();
        __syncthreads();
        STORE_TILE();
        __syncthreads();
    }
    COMPUTE1();

    int fr   = lane & 15;
    int rowg = (lane >> 4) << 2;
#pragma unroll
    for (int n = 0; n < 4; n++) {
        int gc = bn0 + wc * 64 + n * 16 + fr;
        float bsum = biases[gc] + biases[1024 + gc] + biases[2048 + gc] + biases[3072 + gc];
#pragma unroll
        for (int m = 0; m < 4; m++) {
            size_t gr = (size_t)(bm0 + wr * 64 + m * 16 + rowg);
#pragma unroll
            for (int j = 0; j < 4; j++) {
                out[(gr + j) * 1024 + gc] = acc[m][n][j] + bsum;
            }
        }
    }
#undef LOAD_TILE
#undef STORE_TILE
#undef COMPUTE1
}

// ---------------------------------------------------------------------------
// Fallback B: plain fp32 (no workspace needed)
// ---------------------------------------------------------------------------
__global__ void fallback_conv(const float* __restrict__ x, const float* __restrict__ kern,
                              const float* __restrict__ biases, float* __restrict__ out) {
    __shared__ float xs[1024];
    int row = blockIdx.x;
    int f = (blockIdx.y << 8) + threadIdx.x;
    int batch = row >> 13, s = row & 8191;
    const float* xb = x + (((size_t)batch << 13) << 10);
    float acc = 0.f;
    for (int tap = 0; tap < 4; tap++) {
        int ss = s - tap;
        __syncthreads();
        for (int i = threadIdx.x; i < 1024; i += 256)
            xs[i] = (ss >= 0) ? xb[((size_t)ss << 10) + i] : 0.f;
        __syncthreads();
        const float* kp = kern + ((size_t)tap << 20) + f;
        float a = 0.f;
        for (int d = 0; d < 1024; d++) a += xs[d] * kp[(size_t)d << 10];
        acc += a + biases[(tap << 10) + f];
    }
    out[((size_t)row << 10) + f] = acc;
}

extern "C" void kernel_launch(void* const* d_in, const int* in_sizes, int n_in,
                              void* d_out, int out_size, void* d_ws, size_t ws_size,
                              hipStream_t stream) {
    const float* x      = (const float*)d_in[0];
    const float* kern   = (const float*)d_in[1];
    const float* biases = (const float*)d_in[2];
    float* out = (float*)d_out;

    const size_t xbf_bytes = (size_t)4 * XBATCH * sizeof(__hip_bfloat16); // 67.1 MB
    const size_t kt_bytes  = (size_t)4096 * 1024 * sizeof(__hip_bfloat16); // 8.4 MB

    if (ws_size >= xbf_bytes + kt_bytes) {
        __hip_bfloat16* Xbf = (__hip_bfloat16*)d_ws;
        __hip_bfloat16* Kt  = (__hip_bfloat16*)((char*)d_ws + xbf_bytes);
        x_to_bf16<<<2048, 256, 0, stream>>>(x, Xbf);
        kconv_transpose<<<dim3(128, 32), 256, 0, stream>>>(kern, Kt);
        altconv_gemm2<<<2048, 256, 0, stream>>>(Xbf, Kt, biases, out);
    } else if (ws_size >= kt_bytes) {
        __hip_bfloat16* Kt = (__hip_bfloat16*)d_ws;
        kconv_transpose<<<dim3(128, 32), 256, 0, stream>>>(kern, Kt);
        altconv_gemm<<<2048, 256, 0, stream>>>(x, Kt, biases, out);
    } else {
        fallback_conv<<<dim3(32768, 4), 256, 0, stream>>>(x, kern, biases, out);
    }
}

// Round 3
// 265.550 us; speedup vs baseline: 2.3197x; 1.2356x over previous
//
#include <hip/hip_runtime.h>
#include <hip/hip_bf16.h>

typedef __attribute__((ext_vector_type(4))) float f32x4;
typedef __attribute__((ext_vector_type(8))) short short8;

#define XROWS 8195            // 3 guard rows + 8192
#define XBATCH (XROWS * 1024) // elems per padded batch

__device__ __forceinline__ short f2bf(float f) {
    union { __hip_bfloat16 h; short s; } u;
    u.h = __float2bfloat16(f);
    return u.s;
}

__device__ __forceinline__ void async16(const void* g, void* l) {
    __builtin_amdgcn_global_load_lds(
        (const __attribute__((address_space(1))) unsigned int*)g,
        (__attribute__((address_space(3))) unsigned int*)l, 16, 0, 0);
}

// ---------------------------------------------------------------------------
// Prepass 1: x fp32 [4][8192][1024] -> Xbf bf16 [4][3+8192][1024], guard=0
// ---------------------------------------------------------------------------
__global__ void x_to_bf16(const float* __restrict__ x,
                          __hip_bfloat16* __restrict__ Xbf) {
    size_t idx = (size_t)blockIdx.x * blockDim.x + threadIdx.x;
    if (idx < 1536) {  // zero 4*3*1024 guard elems
        int b = (int)(idx / 384);
        int r = (int)(idx % 384);
        *reinterpret_cast<short8*>(&Xbf[(size_t)b * XBATCH + r * 8]) =
            (short8){0, 0, 0, 0, 0, 0, 0, 0};
    }
    size_t stride = (size_t)gridDim.x * blockDim.x;
    const size_t nvec = (size_t)4 * 8192 * 1024 / 8;
    for (size_t v = idx; v < nvec; v += stride) {
        size_t e = v * 8;
        int b = (int)(e >> 23);
        size_t rem = e & ((1u << 23) - 1);
        f32x4 lo = *reinterpret_cast<const f32x4*>(x + e);
        f32x4 hi = *reinterpret_cast<const f32x4*>(x + e + 4);
        short8 pk;
        pk[0] = f2bf(lo[0]); pk[1] = f2bf(lo[1]); pk[2] = f2bf(lo[2]); pk[3] = f2bf(lo[3]);
        pk[4] = f2bf(hi[0]); pk[5] = f2bf(hi[1]); pk[6] = f2bf(hi[2]); pk[7] = f2bf(hi[3]);
        *reinterpret_cast<short8*>(&Xbf[(size_t)b * XBATCH + 3 * 1024 + rem]) = pk;
    }
}

// ---------------------------------------------------------------------------
// Prepass 2: kernels [4096][1024] fp32 -> Kt [1024][4096] bf16
// ---------------------------------------------------------------------------
__global__ void kconv_transpose(const float* __restrict__ kern,
                                __hip_bfloat16* __restrict__ Kt) {
    __shared__ float tile[32][33];
    int k0 = blockIdx.x << 5;
    int f0 = blockIdx.y << 5;
    int tx = threadIdx.x & 31;
    int ty = threadIdx.x >> 5;
#pragma unroll
    for (int q = 0; q < 4; q++)
        tile[ty + q * 8][tx] = kern[(size_t)(k0 + ty + q * 8) * 1024 + f0 + tx];
    __syncthreads();
#pragma unroll
    for (int q = 0; q < 4; q++)
        Kt[((size_t)(f0 + ty + q * 8) << 12) + k0 + tx] =
            __float2bfloat16(tile[tx][ty + q * 8]);
}

// ---------------------------------------------------------------------------
// Main GEMM, phase-split schedule:
//   256x256 tile, BK=64, 8 waves (2Mx4N), 4 LDS slots of 32KB (ring),
//   raw s_barrier + aged vmcnt(0) (loads in flight across 2 barriers),
//   XOR-swizzled LDS (byte ^= (row&7)<<4) -> conflict-free ds_read_b128,
//   linear LDS dest + inverse-swizzled global source (rule 21),
//   setprio(1) around MFMA cluster.
// ---------------------------------------------------------------------------
__global__ void __launch_bounds__(512, 2)
altconv_gemm3(const __hip_bfloat16* __restrict__ Xbf,  // [4][8195][1024]
              const __hip_bfloat16* __restrict__ Kt,   // [1024][4096]
              const float* __restrict__ biases,        // [4][1024]
              float* __restrict__ out) {               // [32768][1024]
    __shared__ alignas(16) __hip_bfloat16 LS[4 * 16384];  // 128 KiB

    // bijective XCD swizzle (512 blocks % 8 == 0), nt fastest per XCD chunk
    int bid  = blockIdx.x;
    int tid2 = (bid & 7) * 64 + (bid >> 3);
    int mt = tid2 >> 2;           // 0..127
    int nt = tid2 & 3;            // 0..3
    int bm0   = mt << 8;
    int batch = bm0 >> 13;
    int srow0 = bm0 & 8191;
    int bn0   = nt << 8;
    const __hip_bfloat16* xb = Xbf + (size_t)batch * XBATCH;

    int t    = threadIdx.x;
    int lane = t & 63;
    int wid  = t >> 6;            // 0..7
    int wr = wid >> 2, wc = wid & 3;
    int frr = lane & 15, q = lane >> 4;
    int xorv = (frr & 7) << 4;

    // frag read byte offsets (within a 32KB slot): P = r*128 + kbyte ^ xorv
    int rowA[8], rowB[4];
#pragma unroll
    for (int m = 0; m < 8; m++) rowA[m] = (wr * 128 + m * 16 + frr) * 128;
#pragma unroll
    for (int n = 0; n < 4; n++) rowB[n] = (wc * 64 + n * 16 + frr) * 128;
    int kc0 = ((q << 4)) ^ xorv;        // k-slice 0
    int kc1 = (64 + (q << 4)) ^ xorv;   // k-slice 1

    // staging per-thread consts: linear LDS dest P, inverse-swizzled source
    int ldsPe[4], aoff[4], boff[4];
#pragma unroll
    for (int j = 0; j < 4; j++) {
        int P = (j * 512 + t) * 16;                 // linear dest byte
        int L = P ^ (((P >> 7) & 7) << 4);          // logical byte (involution)
        int r  = L >> 7;
        int kb = L & 127;
        ldsPe[j] = P >> 1;                          // element offset in slot
        aoff[j]  = r * 1024 + (kb >> 1);
        boff[j]  = r * 4096 + (kb >> 1);
    }

    f32x4 acc[8][4];
#pragma unroll
    for (int m = 0; m < 8; m++)
#pragma unroll
        for (int n = 0; n < 4; n++) acc[m][n] = (f32x4){0.f, 0.f, 0.f, 0.f};

#define FENCE() asm volatile("" ::: "memory")
#define VMW0()  asm volatile("s_waitcnt vmcnt(0)" ::: "memory")

#define STAGE2(TS, SA, SB) do {                                               \
        int tap_ = (TS) >> 4;                                                 \
        int c0_  = ((TS) & 15) << 6;                                          \
        const __hip_bfloat16* aS_ =                                           \
            xb + (size_t)(srow0 + 3 - tap_) * 1024 + c0_;                     \
        const __hip_bfloat16* bS_ =                                           \
            Kt + ((size_t)bn0 << 12) + ((size_t)(TS) << 6);                   \
        _Pragma("unroll")                                                     \
        for (int j = 0; j < 4; j++) {                                         \
            async16(aS_ + aoff[j], &LS[(SA) * 16384 + ldsPe[j]]);             \
            async16(bS_ + boff[j], &LS[(SB) * 16384 + ldsPe[j]]);             \
        }                                                                     \
    } while (0)

#define LOADF(SA, SB, KC) do {                                                \
        _Pragma("unroll")                                                     \
        for (int m = 0; m < 8; m++)                                           \
            af[m] = *reinterpret_cast<const short8*>(                         \
                &LS[(SA) * 16384 + ((rowA[m] + (KC)) >> 1)]);                 \
        _Pragma("unroll")                                                     \
        for (int n = 0; n < 4; n++)                                           \
            bf4[n] = *reinterpret_cast<const short8*>(                        \
                &LS[(SB) * 16384 + ((rowB[n] + (KC)) >> 1)]);                 \
    } while (0)

#define DOMFMA() do {                                                         \
        __builtin_amdgcn_s_setprio(1);                                        \
        _Pragma("unroll")                                                     \
        for (int m = 0; m < 8; m++)                                           \
            _Pragma("unroll")                                                 \
            for (int n = 0; n < 4; n++)                                       \
                acc[m][n] = __builtin_amdgcn_mfma_f32_16x16x32_bf16(          \
                    af[m], bf4[n], acc[m][n], 0, 0, 0);                       \
        __builtin_amdgcn_s_setprio(0);                                        \
    } while (0)

    // prologue: stage tile 0 into slots 0,1
    STAGE2(0, 0, 1);

    for (int it = 0; it < 32; ++it) {
        int T1 = (it << 1) + 1;
        {   // tile 2it, k-slice 0 — stage tile 2it+1 into slots 2,3
            VMW0();
            __builtin_amdgcn_s_barrier();
            FENCE();
            short8 af[8], bf4[4];
            LOADF(0, 1, kc0);
            STAGE2(T1, 2, 3);
            DOMFMA();
        }
        {   // tile 2it, k-slice 1
            __builtin_amdgcn_s_barrier();
            FENCE();
            short8 af[8], bf4[4];
            LOADF(0, 1, kc1);
            DOMFMA();
        }
        {   // tile 2it+1, k-slice 0 — stage tile 2it+2 into slots 0,1
            VMW0();
            __builtin_amdgcn_s_barrier();
            FENCE();
            short8 af[8], bf4[4];
            LOADF(2, 3, kc0);
            if (it < 31) STAGE2(T1 + 1, 0, 1);
            DOMFMA();
        }
        {   // tile 2it+1, k-slice 1
            __builtin_amdgcn_s_barrier();
            FENCE();
            short8 af[8], bf4[4];
            LOADF(2, 3, kc1);
            DOMFMA();
        }
    }

    // epilogue: C/D layout col=lane&15, row=(lane>>4)*4+j  [m89]
    int fr   = lane & 15;
    int rowg = (lane >> 4) << 2;
#pragma unroll
    for (int n = 0; n < 4; n++) {
        int gc = bn0 + wc * 64 + n * 16 + fr;
        float bsum = biases[gc] + biases[1024 + gc] + biases[2048 + gc] + biases[3072 + gc];
#pragma unroll
        for (int m = 0; m < 8; m++) {
            size_t gr = (size_t)(bm0 + wr * 128 + m * 16 + rowg);
#pragma unroll
            for (int j = 0; j < 4; j++) {
                out[(gr + j) * 1024 + gc] = acc[m][n][j] + bsum;
            }
        }
    }
#undef STAGE2
#undef LOADF
#undef DOMFMA
#undef FENCE
#undef VMW0
}

// ---------------------------------------------------------------------------
// Fallback A (ws >= 8.4MB): round-1 reg-staged GEMM (verified correct)
// ---------------------------------------------------------------------------
#define LDA 72
__global__ void __launch_bounds__(256, 2)
altconv_gemm(const float* __restrict__ x,
             const __hip_bfloat16* __restrict__ Kt,
             const float* __restrict__ biases,
             float* __restrict__ out) {
    __shared__ alignas(16) __hip_bfloat16 As[128 * LDA];
    __shared__ alignas(16) __hip_bfloat16 Bs[128 * LDA];

    int bid  = blockIdx.x;
    int tid2 = (bid & 7) * 256 + (bid >> 3);
    int mt = tid2 >> 3;
    int nt = tid2 & 7;
    int bm0   = mt * 128;
    int batch = bm0 >> 13;
    int srow0 = bm0 & 8191;
    int bn0   = nt * 128;
    const float* xb = x + (((size_t)batch << 13) << 10);

    int t    = threadIdx.x;
    int lane = t & 63;
    int wid  = t >> 6;
    int wr = wid >> 1, wc = wid & 1;
    int sr   = t >> 1;
    int sseg = t & 1;

    f32x4 acc[4][4];
#pragma unroll
    for (int m = 0; m < 4; m++)
#pragma unroll
        for (int n = 0; n < 4; n++) acc[m][n] = (f32x4){0.f, 0.f, 0.f, 0.f};

    f32x4 aR[8];
    f32x4 bR[4];

#define LOAD_TILE(kt) do {                                                        \
        int tap = (kt) >> 4;                                                      \
        int c0  = ((kt) & 15) << 6;                                               \
        int s   = srow0 + sr - tap;                                               \
        if (s >= 0) {                                                             \
            const float* asrc = xb + ((size_t)s << 10) + c0 + sseg * 32;          \
            _Pragma("unroll")                                                     \
            for (int j = 0; j < 8; j++)                                           \
                aR[j] = *reinterpret_cast<const f32x4*>(asrc + j * 4);            \
        } else {                                                                  \
            _Pragma("unroll")                                                     \
            for (int j = 0; j < 8; j++) aR[j] = (f32x4){0.f, 0.f, 0.f, 0.f};      \
        }                                                                         \
        const __hip_bfloat16* bsrc =                                              \
            Kt + ((size_t)(bn0 + sr) << 12) + (kt) * 64 + sseg * 32;              \
        _Pragma("unroll")                                                         \
        for (int j = 0; j < 4; j++)                                              \
            bR[j] = *reinterpret_cast<const f32x4*>(bsrc + j * 8);                \
    } while (0)

#define STORE_TILE() do {                                                         \
        _Pragma("unroll")                                                         \
        for (int j = 0; j < 4; j++) {                                             \
            short8 pk;                                                            \
            f32x4 lo = aR[2 * j], hi = aR[2 * j + 1];                             \
            pk[0] = f2bf(lo[0]); pk[1] = f2bf(lo[1]);                             \
            pk[2] = f2bf(lo[2]); pk[3] = f2bf(lo[3]);                             \
            pk[4] = f2bf(hi[0]); pk[5] = f2bf(hi[1]);                             \
            pk[6] = f2bf(hi[2]); pk[7] = f2bf(hi[3]);                             \
            *reinterpret_cast<short8*>(&As[sr * LDA + (sseg * 4 + j) * 8]) = pk;  \
        }                                                                         \
        _Pragma("unroll")                                                         \
        for (int j = 0; j < 4; j++)                                               \
            *reinterpret_cast<f32x4*>(&Bs[sr * LDA + (sseg * 4 + j) * 8]) = bR[j];\
    } while (0)

#define COMPUTE1() do {                                                           \
        _Pragma("unroll")                                                         \
        for (int ks = 0; ks < 2; ks++) {                                          \
            short8 af[4], bfv[4];                                                 \
            int koff = ks * 32 + ((lane >> 4) << 3);                              \
            int frr2  = lane & 15;                                                \
            _Pragma("unroll")                                                     \
            for (int m = 0; m < 4; m++)                                           \
                af[m] = *reinterpret_cast<const short8*>(                         \
                    &As[(wr * 64 + m * 16 + frr2) * LDA + koff]);                 \
            _Pragma("unroll")                                                     \
            for (int n = 0; n < 4; n++)                                           \
                bfv[n] = *reinterpret_cast<const short8*>(                        \
                    &Bs[(wc * 64 + n * 16 + frr2) * LDA + koff]);                 \
            _Pragma("unroll")                                                     \
            for (int m = 0; m < 4; m++)                                           \
                _Pragma("unroll")                                                 \
                for (int n = 0; n < 4; n++)                                       \
                    acc[m][n] = __builtin_amdgcn_mfma_f32_16x16x32_bf16(          \
                        af[m], bfv[n], acc[m][n], 0, 0, 0);                       \
        }                                                                         \
    } while (0)

    LOAD_TILE(0);
    STORE_TILE();
    __syncthreads();
    for (int kt = 0; kt < 63; kt++) {
        LOAD_TILE(kt + 1);
        COMPUTE1();
        __syncthreads();
        STORE_TILE();
        __syncthreads();
    }
    COMPUTE1();

    int fr   = lane & 15;
    int rowg = (lane >> 4) << 2;
#pragma unroll
    for (int n = 0; n < 4; n++) {
        int gc = bn0 + wc * 64 + n * 16 + fr;
        float bsum = biases[gc] + biases[1024 + gc] + biases[2048 + gc] + biases[3072 + gc];
#pragma unroll
        for (int m = 0; m < 4; m++) {
            size_t gr = (size_t)(bm0 + wr * 64 + m * 16 + rowg);
#pragma unroll
            for (int j = 0; j < 4; j++) {
                out[(gr + j) * 1024 + gc] = acc[m][n][j] + bsum;
            }
        }
    }
#undef LOAD_TILE
#undef STORE_TILE
#undef COMPUTE1
}

// ---------------------------------------------------------------------------
// Fallback B: plain fp32 (no workspace needed)
// ---------------------------------------------------------------------------
__global__ void fallback_conv(const float* __restrict__ x, const float* __restrict__ kern,
                              const float* __restrict__ biases, float* __restrict__ out) {
    __shared__ float xs[1024];
    int row = blockIdx.x;
    int f = (blockIdx.y << 8) + threadIdx.x;
    int batch = row >> 13, s = row & 8191;
    const float* xb = x + (((size_t)batch << 13) << 10);
    float acc = 0.f;
    for (int tap = 0; tap < 4; tap++) {
        int ss = s - tap;
        __syncthreads();
        for (int i = threadIdx.x; i < 1024; i += 256)
            xs[i] = (ss >= 0) ? xb[((size_t)ss << 10) + i] : 0.f;
        __syncthreads();
        const float* kp = kern + ((size_t)tap << 20) + f;
        float a = 0.f;
        for (int d = 0; d < 1024; d++) a += xs[d] * kp[(size_t)d << 10];
        acc += a + biases[(tap << 10) + f];
    }
    out[((size_t)row << 10) + f] = acc;
}

extern "C" void kernel_launch(void* const* d_in, const int* in_sizes, int n_in,
                              void* d_out, int out_size, void* d_ws, size_t ws_size,
                              hipStream_t stream) {
    const float* x      = (const float*)d_in[0];
    const float* kern   = (const float*)d_in[1];
    const float* biases = (const float*)d_in[2];
    float* out = (float*)d_out;

    const size_t xbf_bytes = (size_t)4 * XBATCH * sizeof(__hip_bfloat16); // 67.1 MB
    const size_t kt_bytes  = (size_t)4096 * 1024 * sizeof(__hip_bfloat16); // 8.4 MB

    if (ws_size >= xbf_bytes + kt_bytes) {
        __hip_bfloat16* Xbf = (__hip_bfloat16*)d_ws;
        __hip_bfloat16* Kt  = (__hip_bfloat16*)((char*)d_ws + xbf_bytes);
        x_to_bf16<<<2048, 256, 0, stream>>>(x, Xbf);
        kconv_transpose<<<dim3(128, 32), 256, 0, stream>>>(kern, Kt);
        altconv_gemm3<<<512, 512, 0, stream>>>(Xbf, Kt, biases, out);
    } else if (ws_size >= kt_bytes) {
        __hip_bfloat16* Kt = (__hip_bfloat16*)d_ws;
        kconv_transpose<<<dim3(128, 32), 256, 0, stream>>>(kern, Kt);
        altconv_gemm<<<2048, 256, 0, stream>>>(x, Kt, biases, out);
    } else {
        fallback_conv<<<dim3(32768, 4), 256, 0, stream>>>(x, kern, biases, out);
    }
}